// Round 9
// baseline (460.336 us; speedup 1.0000x reference)
//
#include <hip/hip_runtime.h>
#include <math.h>

#pragma clang fp contract(off)

typedef unsigned int u32;

#define N_NEUR 262144                 // 32*8192 neurons
#define TT     128                    // time steps
#define OB     ((size_t)N_NEUR * TT)  // floats in spike region of out
#define PB     128                    // persistent blocks (<= 256 CUs -> co-resident)
#define PT     512                    // threads/block (8 waves)
#define NW     8
#define GUARD_MAX (1 << 16)           // bounded spin: terminate, never hang

__device__ __forceinline__ float f4c(const float4 v, int c) {
  switch (c & 3) { case 0: return v.x; case 1: return v.y; case 2: return v.z; default: return v.w; }
}
__device__ __forceinline__ float wredf(float v) {
#pragma unroll
  for (int o = 32; o; o >>= 1) v += __shfl_xor(v, o);
  return v;
}
__device__ __forceinline__ int wredi(int v) {
#pragma unroll
  for (int o = 32; o; o >>= 1) v += __shfl_xor(v, o);
  return v;
}

__launch_bounds__(PT)
__global__ void snn_persist(const float* __restrict__ in, const float* __restrict__ tsp,
                            const float* __restrict__ abp, float* __restrict__ out,
                            u32* __restrict__ bits2, u32* __restrict__ g_acc,
                            float* __restrict__ wm, float* __restrict__ wt,
                            float* __restrict__ wa)
{
#pragma clang fp contract(off)
  const int tid  = threadIdx.x;
  const int bid  = blockIdx.x;
  const int gtid = bid * PT + tid;          // 0..65535, 4 neurons each
  const int lane = tid & 63;
  const int wv   = tid >> 6;

  // Verified-exact constants (R6-R8, absmax 0.0): CR expf of the f32 quotients.
  const float alp = __uint_as_float(0x3F7383C5u);
  const float bet = __uint_as_float(0x3F519856u);
  const float gma = __uint_as_float(0x3F7D73E8u);
  const float omg = 1.0f - gma;
  const float tsv = tsp[0];
  const float abv = abp[0];

  float s0=0.f,s1=0.f,s2=0.f,s3=0.f;
  float m0=0.f,m1=0.f,m2=0.f,m3=0.f;
  float a0=0.f,a1=0.f,a2=0.f,a3=0.f;
  float ema = 0.f;
  float sc  = (tsv + 0.1f * fmaxf(ema - 0.01f, 0.0f)) + abv;

  __shared__ int   shc[NW];
  __shared__ float shm[NW];
  __shared__ u32   s_tot;

  const int n0 = gtid * 4;
  const float* r0 = in + (size_t)(n0 + 0) * TT;
  const float* r1 = in + (size_t)(n0 + 1) * TT;
  const float* r2 = in + (size_t)(n0 + 2) * TT;
  const float* r3 = in + (size_t)(n0 + 3) * TT;

  // One step: neuron math (byte-identical to R6-R8) + single packed
  // fetch_add publish + one-word poll (2-leg sync, the minimum).
  // Packed word: low 8 bits = blocks-done, bits 8..26 = spike count total.
#define STEPSYNC(I0, I1, I2, I3, T_) {                                         \
    s0 = __builtin_fmaf(bet, s0, (I0));                                        \
    m0 = __builtin_fmaf(alp, m0, s0);                                          \
    const float aw0 = omg * m0;                                                \
    a0 = __builtin_fmaf(gma, a0, aw0);                                         \
    const float th0 = __builtin_fmaf(0.1f, a0, sc);                            \
    const bool sp0 = (m0 >= th0); if (sp0) m0 = m0 - th0;                      \
    s1 = __builtin_fmaf(bet, s1, (I1));                                        \
    m1 = __builtin_fmaf(alp, m1, s1);                                          \
    const float aw1 = omg * m1;                                                \
    a1 = __builtin_fmaf(gma, a1, aw1);                                         \
    const float th1 = __builtin_fmaf(0.1f, a1, sc);                            \
    const bool sp1 = (m1 >= th1); if (sp1) m1 = m1 - th1;                      \
    s2 = __builtin_fmaf(bet, s2, (I2));                                        \
    m2 = __builtin_fmaf(alp, m2, s2);                                          \
    const float aw2 = omg * m2;                                                \
    a2 = __builtin_fmaf(gma, a2, aw2);                                         \
    const float th2 = __builtin_fmaf(0.1f, a2, sc);                            \
    const bool sp2 = (m2 >= th2); if (sp2) m2 = m2 - th2;                      \
    s3 = __builtin_fmaf(bet, s3, (I3));                                        \
    m3 = __builtin_fmaf(alp, m3, s3);                                          \
    const float aw3 = omg * m3;                                                \
    a3 = __builtin_fmaf(gma, a3, aw3);                                         \
    const float th3 = __builtin_fmaf(0.1f, a3, sc);                            \
    const bool sp3 = (m3 >= th3); if (sp3) m3 = m3 - th3;                      \
    int cnt = (int)sp0 + (int)sp1 + (int)sp2 + (int)sp3;                       \
    cnt = wredi(cnt);                                                          \
    if (lane == 0) shc[wv] = cnt;                                              \
    __syncthreads();                                                           \
    if (wv == 0 && lane == 0) {                                                \
      int bc = ((((((shc[0] + shc[1]) + shc[2]) + shc[3]) + shc[4])            \
                 + shc[5]) + shc[6]) + shc[7];                                 \
      __hip_atomic_fetch_add(&g_acc[(T_)], 1u | ((u32)bc << 8),                \
                             __ATOMIC_RELAXED, __HIP_MEMORY_SCOPE_AGENT);      \
    }                                                                          \
    /* hidden under the sync round trip: bits pack + trace reductions */       \
    u32 nib = (u32)sp0 | ((u32)sp1 << 1) | ((u32)sp2 << 2) | ((u32)sp3 << 3);  \
    u32 word = nib << (4 * (tid & 7));                                         \
    word |= (u32)__shfl_xor((int)word, 1);                                     \
    word |= (u32)__shfl_xor((int)word, 2);                                     \
    word |= (u32)__shfl_xor((int)word, 4);                                     \
    if ((tid & 7) == 0) bits2[(size_t)(gtid >> 3) * TT + (T_)] = word;         \
    float msum = ((m0 + m1) + m2) + m3;                                        \
    float tsum = ((th0 + th1) + th2) + th3;                                    \
    msum = wredf(msum); tsum = wredf(tsum);                                    \
    if (lane == 0) {                                                           \
      wm[((size_t)(T_) * PB + bid) * NW + wv] = msum;                          \
      wt[((size_t)(T_) * PB + bid) * NW + wv] = tsum;                          \
    }                                                                          \
    if (wv == 0 && lane == 0) {                                                \
      u32 v_; int gd_ = 0;                                                     \
      while (1) {                                                              \
        v_ = __hip_atomic_load(&g_acc[(T_)], __ATOMIC_RELAXED,                 \
                               __HIP_MEMORY_SCOPE_AGENT);                      \
        if ((v_ & 0xFFu) == (u32)PB) break;                                    \
        if (++gd_ > GUARD_MAX) break;                                          \
        __builtin_amdgcn_s_sleep(1);                                           \
      }                                                                        \
      s_tot = v_ >> 8;                                                         \
    }                                                                          \
    __syncthreads();                                                           \
    const float mean_ = (float)s_tot * 3.814697265625e-06f;                    \
    ema = __builtin_fmaf(0.99f, ema, 0.01f * mean_);                           \
    sc  = (tsv + 0.1f * fmaxf(ema - 0.01f, 0.0f)) + abv;                       \
  }

#define LOADC(X0,X1,X2,X3,X4,X5,X6,X7, c) {            \
    X0 = *(const float4*)(r0 + (c) * 8);               \
    X1 = *(const float4*)(r0 + (c) * 8 + 4);           \
    X2 = *(const float4*)(r1 + (c) * 8);               \
    X3 = *(const float4*)(r1 + (c) * 8 + 4);           \
    X4 = *(const float4*)(r2 + (c) * 8);               \
    X5 = *(const float4*)(r2 + (c) * 8 + 4);           \
    X6 = *(const float4*)(r3 + (c) * 8);               \
    X7 = *(const float4*)(r3 + (c) * 8 + 4); }

#define DOCHUNK(X0,X1,X2,X3,X4,X5,X6,X7, c) {                     \
    _Pragma("unroll")                                             \
    for (int k = 0; k < 8; ++k) {                                 \
      const float i0_ = (k < 4) ? f4c(X0, k) : f4c(X1, k);        \
      const float i1_ = (k < 4) ? f4c(X2, k) : f4c(X3, k);        \
      const float i2_ = (k < 4) ? f4c(X4, k) : f4c(X5, k);        \
      const float i3_ = (k < 4) ? f4c(X6, k) : f4c(X7, k);        \
      STEPSYNC(i0_, i1_, i2_, i3_, (c) * 8 + k);                  \
    } }

  float4 A0,A1,A2,A3,A4,A5,A6,A7;
  float4 B0,B1,B2,B3,B4,B5,B6,B7;

  LOADC(A0,A1,A2,A3,A4,A5,A6,A7, 0);
  for (int cc = 0; cc < 8; ++cc) {
    LOADC(B0,B1,B2,B3,B4,B5,B6,B7, 2 * cc + 1);         // prefetch odd chunk
    DOCHUNK(A0,A1,A2,A3,A4,A5,A6,A7, 2 * cc);
    if (cc < 7) LOADC(A0,A1,A2,A3,A4,A5,A6,A7, 2 * cc + 2);  // prefetch next even
    DOCHUNK(B0,B1,B2,B3,B4,B5,B6,B7, 2 * cc + 1);
  }
#undef DOCHUNK
#undef LOADC
#undef STEPSYNC

  // final adaptation partial + final ema
  float asum = ((a0 + a1) + a2) + a3;
  asum = wredf(asum);
  __syncthreads();
  if (lane == 0) shm[wv] = asum;
  __syncthreads();
  if (tid == 0) {
    float bs = 0.f;
    for (int w = 0; w < NW; ++w) bs += shm[w];
    wa[bid] = bs;
    if (bid == 0) out[OB + 256] = ema;   // ema after step 127
  }
}

// Deterministic fold of per-wave trace partials (1024 per step, fixed order).
__launch_bounds__(256)
__global__ void snn_finish(const float* __restrict__ wm, const float* __restrict__ wt,
                           const float* __restrict__ wa, float* __restrict__ out)
{
#pragma clang fp contract(off)
  const int tid = threadIdx.x;
  const float inv = 3.814697265625e-06f;   // 2^-18
  if (tid < 128) {
    float s = 0.f;
    for (int j = 0; j < PB * NW; ++j) s += wm[(size_t)tid * PB * NW + j];
    out[OB + tid] = s * inv;
  } else {
    const int t = tid - 128;
    float s = 0.f;
    for (int j = 0; j < PB * NW; ++j) s += wt[(size_t)t * PB * NW + j];
    out[OB + 128 + t] = s * inv;
  }
  if (tid == 0) {
    float s = 0.f;
    for (int b = 0; b < PB; ++b) s += wa[b];
    out[OB + 257] = s * inv;
  }
}

// bits2[word][t] -> float spikes [n][t]; uint4 reads + float4 writes, coalesced.
__global__ void snn_expand(const u32* __restrict__ bits2, float* __restrict__ outF)
{
  const int gtid = blockIdx.x * blockDim.x + threadIdx.x;
  const int wave = gtid >> 6, lane = gtid & 63;
  const int nwaves = (gridDim.x * blockDim.x) >> 6;
  const int nloc = lane >> 5;     // which neuron of the pair
  const int tq   = lane & 31;     // float4 chunk over t
  for (int pair = wave; pair < N_NEUR / 2; pair += nwaves) {
    const int n = 2 * pair + nloc;
    const uint4 w = *(const uint4*)(bits2 + (size_t)(n >> 5) * TT + 4 * tq);
    const int b = n & 31;
    float4 f;
    f.x = (float)((w.x >> b) & 1u);
    f.y = (float)((w.y >> b) & 1u);
    f.z = (float)((w.z >> b) & 1u);
    f.w = (float)((w.w >> b) & 1u);
    ((float4*)outF)[(size_t)n * (TT / 4) + tq] = f;
  }
}

extern "C" void kernel_launch(void* const* d_in, const int* in_sizes, int n_in,
                              void* d_out, int out_size, void* d_ws, size_t ws_size,
                              hipStream_t stream)
{
  const float* in  = (const float*)d_in[0];
  const float* tsp = (const float*)d_in[1];
  const float* abp = (const float*)d_in[2];
  float* out = (float*)d_out;
  unsigned char* ws = (unsigned char*)d_ws;

  if (ws_size < 5244000u) return;   // need ~5.01 MiB scratch

  u32*   bits2 = (u32*)(ws);                    // 4 MiB   [8192 words][128 t]
  float* wm    = (float*)(ws + 4194304);        // 512 KiB [128 t][128 b][8 w]
  float* wt    = (float*)(ws + 4718592);        // 512 KiB
  u32*   g_acc = (u32*)(ws + 5242880);          // 512 B   [128 t] packed done|count
  float* wa    = (float*)(ws + 5243392);        // 512 B

  hipMemsetAsync(g_acc, 0, 512, stream);        // zero packed accumulators

  snn_persist<<<dim3(PB), dim3(PT), 0, stream>>>(in, tsp, abp, out,
                                                 bits2, g_acc, wm, wt, wa);
  snn_finish<<<dim3(1), dim3(256), 0, stream>>>(wm, wt, wa, out);
  snn_expand<<<dim3(2048), dim3(256), 0, stream>>>(bits2, out);
}

// Round 10
// 383.157 us; speedup vs baseline: 1.2014x; 1.2014x over previous
//
#include <hip/hip_runtime.h>
#include <math.h>

#pragma clang fp contract(off)

typedef unsigned int u32;
typedef unsigned long long u64;

#define N_NEUR 262144                 // 32*8192 neurons
#define TT     128                    // time steps
#define OB     ((size_t)N_NEUR * TT)  // floats in spike region of out
#define PB     128                    // worker blocks (+1 master; 129 <= 256 CUs)
#define PT     512                    // threads/block (8 waves)
#define NW     8
#define WGUARD (1 << 16)              // bounded spins: terminate, never hang
#define MGUARD (1 << 17)

__device__ __forceinline__ float wredf(float v) {
#pragma unroll
  for (int o = 32; o; o >>= 1) v += __shfl_xor(v, o);
  return v;
}
__device__ __forceinline__ int wredi(int v) {
#pragma unroll
  for (int o = 32; o; o >>= 1) v += __shfl_xor(v, o);
  return v;
}

__launch_bounds__(PT)
__global__ void snn_persist(const float* __restrict__ in, const float* __restrict__ tsp,
                            const float* __restrict__ abp, float* __restrict__ out,
                            u32* __restrict__ bits2, u32* __restrict__ g_cnt,
                            u64* __restrict__ g_sc, float* __restrict__ wm,
                            float* __restrict__ wt, float* __restrict__ wa)
{
#pragma clang fp contract(off)
  const int tid  = threadIdx.x;
  const int bid  = blockIdx.x;
  const int lane = tid & 63;
  const int wv   = tid >> 6;

  if (bid == PB) {
    // ---------------- dedicated master: sync only, no neuron work ----------
    if (wv != 0) return;
    const float tsv = tsp[0], abv = abp[0];
    float ema = 0.0f;
    for (int t = 0; t < TT; ++t) {
      const u32* slots = g_cnt + (size_t)t * PB;
      u32 v0, v1; int gd = 0;
      while (1) {  // tight poll: 1 wave, 8 lines, no congestion
        v0 = __hip_atomic_load(&slots[lane],      __ATOMIC_RELAXED, __HIP_MEMORY_SCOPE_AGENT);
        v1 = __hip_atomic_load(&slots[lane + 64], __ATOMIC_RELAXED, __HIP_MEMORY_SCOPE_AGENT);
        if (__all(v0 != 0u && v1 != 0u)) break;
        if (++gd > MGUARD) break;
      }
      int ss = (int)(v0 ? v0 - 1u : 0u) + (int)(v1 ? v1 - 1u : 0u);
      ss = wredi(ss);
      const float mean = (float)ss * 3.814697265625e-06f;   // *2^-18, exact
      ema = __builtin_fmaf(0.99f, ema, 0.01f * mean);       // verified-exact chain
      if (t < TT - 1) {
        const float scn = (tsv + 0.1f * fmaxf(ema - 0.01f, 0.0f)) + abv;
        const u64 pkt = ((u64)__float_as_uint(scn) << 32) | 1ull;
        if (lane < 16)   // replicate to 16 lines: <=8 worker blocks per line
          __hip_atomic_store(&g_sc[(size_t)(t + 1) * 16 + lane], pkt,
                             __ATOMIC_RELAXED, __HIP_MEMORY_SCOPE_AGENT);
      }
    }
    if (lane == 0) out[OB + 256] = ema;   // final ema (after step 127)
    return;
  }

  // ---------------- worker ------------------------------------------------
  const int gtid = bid * PT + tid;          // 0..65535, 4 neurons each

  // Verified-exact constants (R6-R9, absmax 0.0): CR expf of f32 quotients.
  const float alp = __uint_as_float(0x3F7383C5u);
  const float bet = __uint_as_float(0x3F519856u);
  const float gma = __uint_as_float(0x3F7D73E8u);
  const float omg = 1.0f - gma;
  const float tsv = tsp[0];
  const float abv = abp[0];

  const int n0 = gtid * 4;
  const float4* q0 = (const float4*)(in + (size_t)(n0 + 0) * TT);
  const float4* q1 = (const float4*)(in + (size_t)(n0 + 1) * TT);
  const float4* q2 = (const float4*)(in + (size_t)(n0 + 2) * TT);
  const float4* q3 = (const float4*)(in + (size_t)(n0 + 3) * TT);

  float4 c0 = q0[0], c1 = q1[0], c2 = q2[0], c3 = q3[0];   // G(q)   steps 4q..4q+3
  float4 f0 = q0[1], f1 = q1[1], f2 = q2[1], f3 = q3[1];   // G(q+1)

  // advance state from zeros to step 0 (byte-identical fma chain)
  float S0,S1,S2,S3, Mp0,Mp1,Mp2,Mp3, A0,A1,A2,A3;
  S0 = __builtin_fmaf(bet, 0.0f, c0.x); Mp0 = __builtin_fmaf(alp, 0.0f, S0);
  A0 = __builtin_fmaf(gma, 0.0f, omg * Mp0);
  S1 = __builtin_fmaf(bet, 0.0f, c1.x); Mp1 = __builtin_fmaf(alp, 0.0f, S1);
  A1 = __builtin_fmaf(gma, 0.0f, omg * Mp1);
  S2 = __builtin_fmaf(bet, 0.0f, c2.x); Mp2 = __builtin_fmaf(alp, 0.0f, S2);
  A2 = __builtin_fmaf(gma, 0.0f, omg * Mp2);
  S3 = __builtin_fmaf(bet, 0.0f, c3.x); Mp3 = __builtin_fmaf(alp, 0.0f, S3);
  A3 = __builtin_fmaf(gma, 0.0f, omg * Mp3);

  float sc;
  { const float homeo = 0.1f * fmaxf(0.0f - 0.01f, 0.0f);  // ema(pre)=0 -> 0
    sc = (tsv + homeo) + abv; }

  __shared__ int   shc[NW];
  __shared__ float shm[NW];
  __shared__ u32   s_sc;

  float M0, M1, M2, M3;   // post-reset membranes of the current step

  // One step. Critical path after detect: threshold/compare/reset/count/
  // publish only. Everything else (bits, traces, input prefetch, state
  // advance to t+1 -- all ema-independent) hides under the sync flight.
#define STEP(T_, IN0, IN1, IN2, IN3) {                                         \
    if ((T_) > 0) {                                                            \
      if (tid == 0) {                                                          \
        u64 v_; int gd_ = 0;                                                   \
        while (1) {                                                            \
          v_ = __hip_atomic_load(&g_sc[(size_t)(T_) * 16 + (bid & 15)],        \
                                 __ATOMIC_RELAXED, __HIP_MEMORY_SCOPE_AGENT);  \
          if ((u32)v_ != 0u) break;                                            \
          if (++gd_ > WGUARD) break;                                           \
          __builtin_amdgcn_s_sleep(1);                                         \
        }                                                                      \
        s_sc = (u32)(v_ >> 32);                                                \
      }                                                                        \
      __syncthreads();                                                         \
      sc = __uint_as_float(s_sc);                                              \
    }                                                                          \
    const float th0 = __builtin_fmaf(0.1f, A0, sc);                            \
    const float th1 = __builtin_fmaf(0.1f, A1, sc);                            \
    const float th2 = __builtin_fmaf(0.1f, A2, sc);                            \
    const float th3 = __builtin_fmaf(0.1f, A3, sc);                            \
    const bool sp0 = (Mp0 >= th0);  M0 = sp0 ? Mp0 - th0 : Mp0;                \
    const bool sp1 = (Mp1 >= th1);  M1 = sp1 ? Mp1 - th1 : Mp1;                \
    const bool sp2 = (Mp2 >= th2);  M2 = sp2 ? Mp2 - th2 : Mp2;                \
    const bool sp3 = (Mp3 >= th3);  M3 = sp3 ? Mp3 - th3 : Mp3;                \
    int cnt = (int)sp0 + (int)sp1 + (int)sp2 + (int)sp3;                       \
    cnt = wredi(cnt);                                                          \
    if (lane == 0) shc[wv] = cnt;                                              \
    __syncthreads();                                                           \
    if (tid == 0) {                                                            \
      const int bc = ((((((shc[0] + shc[1]) + shc[2]) + shc[3]) + shc[4])      \
                       + shc[5]) + shc[6]) + shc[7];                           \
      __hip_atomic_store(&g_cnt[(size_t)(T_) * PB + bid], (u32)bc + 1u,        \
                         __ATOMIC_RELAXED, __HIP_MEMORY_SCOPE_AGENT);          \
    }                                                                          \
    /* ---- hidden under sync flight ---- */                                   \
    u32 nib = (u32)sp0 | ((u32)sp1 << 1) | ((u32)sp2 << 2) | ((u32)sp3 << 3);  \
    u32 word = nib << (4 * (tid & 7));                                         \
    word |= (u32)__shfl_xor((int)word, 1);                                     \
    word |= (u32)__shfl_xor((int)word, 2);                                     \
    word |= (u32)__shfl_xor((int)word, 4);                                     \
    if ((tid & 7) == 0) bits2[(size_t)(gtid >> 3) * TT + (T_)] = word;         \
    float msum = ((M0 + M1) + M2) + M3;                                        \
    float tsum = ((th0 + th1) + th2) + th3;                                    \
    msum = wredf(msum); tsum = wredf(tsum);                                    \
    if (lane == 0) {                                                           \
      wm[((size_t)(T_) * PB + bid) * NW + wv] = msum;                          \
      wt[((size_t)(T_) * PB + bid) * NW + wv] = tsum;                          \
    }                                                                          \
    if ((T_) < TT - 1) {  /* ema-independent advance to step T_+1 */           \
      S0 = __builtin_fmaf(bet, S0, (IN0));                                     \
      Mp0 = __builtin_fmaf(alp, M0, S0);                                       \
      A0 = __builtin_fmaf(gma, A0, omg * Mp0);                                 \
      S1 = __builtin_fmaf(bet, S1, (IN1));                                     \
      Mp1 = __builtin_fmaf(alp, M1, S1);                                       \
      A1 = __builtin_fmaf(gma, A1, omg * Mp1);                                 \
      S2 = __builtin_fmaf(bet, S2, (IN2));                                     \
      Mp2 = __builtin_fmaf(alp, M2, S2);                                       \
      A2 = __builtin_fmaf(gma, A2, omg * Mp2);                                 \
      S3 = __builtin_fmaf(bet, S3, (IN3));                                     \
      Mp3 = __builtin_fmaf(alp, M3, S3);                                       \
      A3 = __builtin_fmaf(gma, A3, omg * Mp3);                                 \
    }                                                                          \
  }

#pragma unroll 1
  for (int q = 0; q < 32; ++q) {
    float4 p0 = {0,0,0,0}, p1 = {0,0,0,0}, p2 = {0,0,0,0}, p3 = {0,0,0,0};
    if (q < 30) { p0 = q0[q + 2]; p1 = q1[q + 2]; p2 = q2[q + 2]; p3 = q3[q + 2]; }
    const int tb = 4 * q;
    STEP(tb + 0, c0.y, c1.y, c2.y, c3.y)
    STEP(tb + 1, c0.z, c1.z, c2.z, c3.z)
    STEP(tb + 2, c0.w, c1.w, c2.w, c3.w)
    STEP(tb + 3, f0.x, f1.x, f2.x, f3.x)
    c0 = f0; c1 = f1; c2 = f2; c3 = f3;
    f0 = p0; f1 = p1; f2 = p2; f3 = p3;
  }
#undef STEP

  // final adaptation partial: A holds a(127)
  float asum = ((A0 + A1) + A2) + A3;
  asum = wredf(asum);
  if (lane == 0) shm[wv] = asum;
  __syncthreads();
  if (tid == 0) {
    float bs = 0.f;
    for (int w = 0; w < NW; ++w) bs += shm[w];
    wa[bid] = bs;
  }
}

// Deterministic fold of per-wave trace partials (1024 per step, fixed order).
__launch_bounds__(256)
__global__ void snn_finish(const float* __restrict__ wm, const float* __restrict__ wt,
                           const float* __restrict__ wa, float* __restrict__ out)
{
#pragma clang fp contract(off)
  const int tid = threadIdx.x;
  const float inv = 3.814697265625e-06f;   // 2^-18
  if (tid < 128) {
    float s = 0.f;
    for (int j = 0; j < PB * NW; ++j) s += wm[(size_t)tid * PB * NW + j];
    out[OB + tid] = s * inv;
  } else {
    const int t = tid - 128;
    float s = 0.f;
    for (int j = 0; j < PB * NW; ++j) s += wt[(size_t)t * PB * NW + j];
    out[OB + 128 + t] = s * inv;
  }
  if (tid == 0) {
    float s = 0.f;
    for (int b = 0; b < PB; ++b) s += wa[b];
    out[OB + 257] = s * inv;
  }
}

// bits2[word][t] -> float spikes [n][t]; uint4 reads + float4 writes, coalesced.
__global__ void snn_expand(const u32* __restrict__ bits2, float* __restrict__ outF)
{
  const int gtid = blockIdx.x * blockDim.x + threadIdx.x;
  const int wave = gtid >> 6, lane = gtid & 63;
  const int nwaves = (gridDim.x * blockDim.x) >> 6;
  const int nloc = lane >> 5;     // which neuron of the pair
  const int tq   = lane & 31;     // float4 chunk over t
  for (int pair = wave; pair < N_NEUR / 2; pair += nwaves) {
    const int n = 2 * pair + nloc;
    const uint4 w = *(const uint4*)(bits2 + (size_t)(n >> 5) * TT + 4 * tq);
    const int b = n & 31;
    float4 f;
    f.x = (float)((w.x >> b) & 1u);
    f.y = (float)((w.y >> b) & 1u);
    f.z = (float)((w.z >> b) & 1u);
    f.w = (float)((w.w >> b) & 1u);
    ((float4*)outF)[(size_t)n * (TT / 4) + tq] = f;
  }
}

extern "C" void kernel_launch(void* const* d_in, const int* in_sizes, int n_in,
                              void* d_out, int out_size, void* d_ws, size_t ws_size,
                              hipStream_t stream)
{
  const float* in  = (const float*)d_in[0];
  const float* tsp = (const float*)d_in[1];
  const float* abp = (const float*)d_in[2];
  float* out = (float*)d_out;
  unsigned char* ws = (unsigned char*)d_ws;

  if (ws_size < 5326000u) return;   // need ~5.08 MiB scratch

  u32*   bits2 = (u32*)(ws);                    // 4 MiB   [8192 words][128 t]
  float* wm    = (float*)(ws + 4194304);        // 512 KiB [128 t][128 b][8 w]
  float* wt    = (float*)(ws + 4718592);        // 512 KiB
  u32*   g_cnt = (u32*)(ws + 5242880);          // 64 KiB  [128 t][128 b] count+1
  u64*   g_sc  = (u64*)(ws + 5308416);          // 16 KiB  [128 t][16 lines] flag|sc
  float* wa    = (float*)(ws + 5324800);        // 512 B

  hipMemsetAsync(g_cnt, 0, 81920, stream);      // zero count slots + sc slots

  snn_persist<<<dim3(PB + 1), dim3(PT), 0, stream>>>(in, tsp, abp, out,
                                                     bits2, g_cnt, g_sc, wm, wt, wa);
  snn_finish<<<dim3(1), dim3(256), 0, stream>>>(wm, wt, wa, out);
  snn_expand<<<dim3(2048), dim3(256), 0, stream>>>(bits2, out);
}

// Round 11
// 370.377 us; speedup vs baseline: 1.2429x; 1.0345x over previous
//
#include <hip/hip_runtime.h>
#include <math.h>

#pragma clang fp contract(off)

typedef unsigned int u32;

#define N_NEUR 262144                 // 32*8192 neurons
#define TT     128                    // time steps
#define OB     ((size_t)N_NEUR * TT)  // floats in spike region of out
#define PB     128                    // persistent blocks (<= 256 CUs -> co-resident)
#define PT     512                    // threads/block (8 waves)
#define NW     8
#define NREP   16                     // count-array replicas (8 poller blocks each)
#define WGUARD (1 << 17)              // bounded spins: terminate, never hang

__device__ __forceinline__ float wredf(float v) {
#pragma unroll
  for (int o = 32; o; o >>= 1) v += __shfl_xor(v, o);
  return v;
}
__device__ __forceinline__ int wredi(int v) {
#pragma unroll
  for (int o = 32; o; o >>= 1) v += __shfl_xor(v, o);
  return v;
}

__launch_bounds__(PT)
__global__ void snn_persist(const float* __restrict__ in, const float* __restrict__ tsp,
                            const float* __restrict__ abp, float* __restrict__ out,
                            u32* __restrict__ bits2, u32* __restrict__ g_rep,
                            float* __restrict__ wm, float* __restrict__ wt,
                            float* __restrict__ wa)
{
#pragma clang fp contract(off)
  const int tid  = threadIdx.x;
  const int bid  = blockIdx.x;
  const int gtid = bid * PT + tid;          // 0..65535, 4 neurons each
  const int lane = tid & 63;
  const int wv   = tid >> 6;
  const int rep  = bid & (NREP - 1);        // which replica this block polls

  // Verified-exact constants (R6-R10, absmax 0.0): CR expf of f32 quotients.
  const float alp = __uint_as_float(0x3F7383C5u);
  const float bet = __uint_as_float(0x3F519856u);
  const float gma = __uint_as_float(0x3F7D73E8u);
  const float omg = 1.0f - gma;
  const float tsv = tsp[0];
  const float abv = abp[0];

  const int n0 = gtid * 4;
  const float4* q0 = (const float4*)(in + (size_t)(n0 + 0) * TT);
  const float4* q1 = (const float4*)(in + (size_t)(n0 + 1) * TT);
  const float4* q2 = (const float4*)(in + (size_t)(n0 + 2) * TT);
  const float4* q3 = (const float4*)(in + (size_t)(n0 + 3) * TT);

  float4 c0 = q0[0], c1 = q1[0], c2 = q2[0], c3 = q3[0];   // chunk q   (steps 4q..4q+3)
  float4 f0 = q0[1], f1 = q1[1], f2 = q2[1], f3 = q3[1];   // chunk q+1

  // advance state from zeros to step 0 (byte-identical fma chain)
  float S0,S1,S2,S3, Mp0,Mp1,Mp2,Mp3, A0,A1,A2,A3;
  S0 = __builtin_fmaf(bet, 0.0f, c0.x); Mp0 = __builtin_fmaf(alp, 0.0f, S0);
  A0 = __builtin_fmaf(gma, 0.0f, omg * Mp0);
  S1 = __builtin_fmaf(bet, 0.0f, c1.x); Mp1 = __builtin_fmaf(alp, 0.0f, S1);
  A1 = __builtin_fmaf(gma, 0.0f, omg * Mp1);
  S2 = __builtin_fmaf(bet, 0.0f, c2.x); Mp2 = __builtin_fmaf(alp, 0.0f, S2);
  A2 = __builtin_fmaf(gma, 0.0f, omg * Mp2);
  S3 = __builtin_fmaf(bet, 0.0f, c3.x); Mp3 = __builtin_fmaf(alp, 0.0f, S3);
  A3 = __builtin_fmaf(gma, 0.0f, omg * Mp3);

  float ema = 0.0f;
  float sc  = (tsv + 0.1f * fmaxf(0.0f - 0.01f, 0.0f)) + abv;   // homeo(ema=0)=0

  __shared__ int   shc[NW];
  __shared__ float shm[NW];
  __shared__ u32   s_tot;

  float M0, M1, M2, M3;   // post-reset membranes of the current step

  // One step, 2-leg sync: spike decide -> block count reduce -> publish to all
  // 16 replicas (one store, lanes 0-15) -> [hidden: bits/traces/state advance]
  // -> poll OWN replica all-nonzero -> local integer sum -> ema/sc locally.
#define STEP(T_, IN0, IN1, IN2, IN3) {                                         \
    const float th0 = __builtin_fmaf(0.1f, A0, sc);                            \
    const float th1 = __builtin_fmaf(0.1f, A1, sc);                            \
    const float th2 = __builtin_fmaf(0.1f, A2, sc);                            \
    const float th3 = __builtin_fmaf(0.1f, A3, sc);                            \
    const bool sp0 = (Mp0 >= th0);  M0 = sp0 ? Mp0 - th0 : Mp0;                \
    const bool sp1 = (Mp1 >= th1);  M1 = sp1 ? Mp1 - th1 : Mp1;                \
    const bool sp2 = (Mp2 >= th2);  M2 = sp2 ? Mp2 - th2 : Mp2;                \
    const bool sp3 = (Mp3 >= th3);  M3 = sp3 ? Mp3 - th3 : Mp3;                \
    int cnt = (int)sp0 + (int)sp1 + (int)sp2 + (int)sp3;                       \
    cnt = wredi(cnt);                                                          \
    if (lane == 0) shc[wv] = cnt;                                              \
    __syncthreads();                                                           \
    if (tid < NREP) {  /* each lane publishes to one replica: 1 instruction */ \
      const int bc = ((((((shc[0] + shc[1]) + shc[2]) + shc[3]) + shc[4])      \
                       + shc[5]) + shc[6]) + shc[7];                           \
      __hip_atomic_store(&g_rep[((size_t)(T_) * NREP + tid) * PB + bid],       \
                         (u32)bc + 1u,                                         \
                         __ATOMIC_RELAXED, __HIP_MEMORY_SCOPE_AGENT);          \
    }                                                                          \
    /* ---- hidden under publish-visibility latency ---- */                    \
    u32 nib = (u32)sp0 | ((u32)sp1 << 1) | ((u32)sp2 << 2) | ((u32)sp3 << 3);  \
    u32 word = nib << (4 * (tid & 7));                                         \
    word |= (u32)__shfl_xor((int)word, 1);                                     \
    word |= (u32)__shfl_xor((int)word, 2);                                     \
    word |= (u32)__shfl_xor((int)word, 4);                                     \
    if ((tid & 7) == 0) bits2[(size_t)(gtid >> 3) * TT + (T_)] = word;         \
    float msum = ((M0 + M1) + M2) + M3;                                        \
    float tsum = ((th0 + th1) + th2) + th3;                                    \
    msum = wredf(msum); tsum = wredf(tsum);                                    \
    if (lane == 0) {                                                           \
      wm[((size_t)(T_) * PB + bid) * NW + wv] = msum;                          \
      wt[((size_t)(T_) * PB + bid) * NW + wv] = tsum;                          \
    }                                                                          \
    if ((T_) < TT - 1) {  /* ema-independent advance to step T_+1 */           \
      S0 = __builtin_fmaf(bet, S0, (IN0));                                     \
      Mp0 = __builtin_fmaf(alp, M0, S0);                                       \
      A0 = __builtin_fmaf(gma, A0, omg * Mp0);                                 \
      S1 = __builtin_fmaf(bet, S1, (IN1));                                     \
      Mp1 = __builtin_fmaf(alp, M1, S1);                                       \
      A1 = __builtin_fmaf(gma, A1, omg * Mp1);                                 \
      S2 = __builtin_fmaf(bet, S2, (IN2));                                     \
      Mp2 = __builtin_fmaf(alp, M2, S2);                                       \
      A2 = __builtin_fmaf(gma, A2, omg * Mp2);                                 \
      S3 = __builtin_fmaf(bet, S3, (IN3));                                     \
      Mp3 = __builtin_fmaf(alp, M3, S3);                                       \
      A3 = __builtin_fmaf(gma, A3, omg * Mp3);                                 \
    }                                                                          \
    /* ---- detect on own replica + local exact sum ---- */                    \
    if (wv == 0) {                                                             \
      const u32* slots_ = g_rep + ((size_t)(T_) * NREP + rep) * PB;            \
      u32 v0_, v1_; int gd_ = 0;                                               \
      while (1) {                                                              \
        v0_ = __hip_atomic_load(&slots_[lane],      __ATOMIC_RELAXED,          \
                                __HIP_MEMORY_SCOPE_AGENT);                     \
        v1_ = __hip_atomic_load(&slots_[lane + 64], __ATOMIC_RELAXED,          \
                                __HIP_MEMORY_SCOPE_AGENT);                     \
        if (__all(v0_ != 0u && v1_ != 0u)) break;                              \
        if (++gd_ > WGUARD) break;                                             \
      }                                                                        \
      int ss_ = (int)(v0_ ? v0_ - 1u : 0u) + (int)(v1_ ? v1_ - 1u : 0u);       \
      ss_ = wredi(ss_);                                                        \
      if (lane == 0) s_tot = (u32)ss_;                                         \
    }                                                                          \
    __syncthreads();                                                           \
    const float mean_ = (float)s_tot * 3.814697265625e-06f;  /* *2^-18 */      \
    ema = __builtin_fmaf(0.99f, ema, 0.01f * mean_);                           \
    sc  = (tsv + 0.1f * fmaxf(ema - 0.01f, 0.0f)) + abv;                       \
  }

#pragma unroll 1
  for (int q = 0; q < 32; ++q) {
    float4 p0 = {0,0,0,0}, p1 = {0,0,0,0}, p2 = {0,0,0,0}, p3 = {0,0,0,0};
    if (q < 30) { p0 = q0[q + 2]; p1 = q1[q + 2]; p2 = q2[q + 2]; p3 = q3[q + 2]; }
    const int tb = 4 * q;
    STEP(tb + 0, c0.y, c1.y, c2.y, c3.y)
    STEP(tb + 1, c0.z, c1.z, c2.z, c3.z)
    STEP(tb + 2, c0.w, c1.w, c2.w, c3.w)
    STEP(tb + 3, f0.x, f1.x, f2.x, f3.x)
    c0 = f0; c1 = f1; c2 = f2; c3 = f3;
    f0 = p0; f1 = p1; f2 = p2; f3 = p3;
  }
#undef STEP

  // final adaptation partial: A holds a(127); final ema identical everywhere
  float asum = ((A0 + A1) + A2) + A3;
  asum = wredf(asum);
  if (lane == 0) shm[wv] = asum;
  __syncthreads();
  if (tid == 0) {
    float bs = 0.f;
    for (int w = 0; w < NW; ++w) bs += shm[w];
    wa[bid] = bs;
    if (bid == 0) out[OB + 256] = ema;   // ema after step 127 (exact, local)
  }
}

// Deterministic fold of per-wave trace partials (1024 per step, fixed order).
__launch_bounds__(256)
__global__ void snn_finish(const float* __restrict__ wm, const float* __restrict__ wt,
                           const float* __restrict__ wa, float* __restrict__ out)
{
#pragma clang fp contract(off)
  const int tid = threadIdx.x;
  const float inv = 3.814697265625e-06f;   // 2^-18
  if (tid < 128) {
    float s = 0.f;
    for (int j = 0; j < PB * NW; ++j) s += wm[(size_t)tid * PB * NW + j];
    out[OB + tid] = s * inv;
  } else {
    const int t = tid - 128;
    float s = 0.f;
    for (int j = 0; j < PB * NW; ++j) s += wt[(size_t)t * PB * NW + j];
    out[OB + 128 + t] = s * inv;
  }
  if (tid == 0) {
    float s = 0.f;
    for (int b = 0; b < PB; ++b) s += wa[b];
    out[OB + 257] = s * inv;
  }
}

// bits2[word][t] -> float spikes [n][t]; uint4 reads + float4 writes, coalesced.
__global__ void snn_expand(const u32* __restrict__ bits2, float* __restrict__ outF)
{
  const int gtid = blockIdx.x * blockDim.x + threadIdx.x;
  const int wave = gtid >> 6, lane = gtid & 63;
  const int nwaves = (gridDim.x * blockDim.x) >> 6;
  const int nloc = lane >> 5;     // which neuron of the pair
  const int tq   = lane & 31;     // float4 chunk over t
  for (int pair = wave; pair < N_NEUR / 2; pair += nwaves) {
    const int n = 2 * pair + nloc;
    const uint4 w = *(const uint4*)(bits2 + (size_t)(n >> 5) * TT + 4 * tq);
    const int b = n & 31;
    float4 f;
    f.x = (float)((w.x >> b) & 1u);
    f.y = (float)((w.y >> b) & 1u);
    f.z = (float)((w.z >> b) & 1u);
    f.w = (float)((w.w >> b) & 1u);
    ((float4*)outF)[(size_t)n * (TT / 4) + tq] = f;
  }
}

extern "C" void kernel_launch(void* const* d_in, const int* in_sizes, int n_in,
                              void* d_out, int out_size, void* d_ws, size_t ws_size,
                              hipStream_t stream)
{
  const float* in  = (const float*)d_in[0];
  const float* tsp = (const float*)d_in[1];
  const float* abp = (const float*)d_in[2];
  float* out = (float*)d_out;
  unsigned char* ws = (unsigned char*)d_ws;

  if (ws_size < 6292000u) return;   // need ~6.0 MiB scratch

  u32*   bits2 = (u32*)(ws);                    // 4 MiB   [8192 words][128 t]
  float* wm    = (float*)(ws + 4194304);        // 512 KiB [128 t][128 b][8 w]
  float* wt    = (float*)(ws + 4718592);        // 512 KiB
  u32*   g_rep = (u32*)(ws + 5242880);          // 1 MiB   [128 t][16 rep][128 slot]
  float* wa    = (float*)(ws + 6291456);        // 512 B

  hipMemsetAsync(g_rep, 0, 1048576, stream);    // zero replica slots (in-graph)

  snn_persist<<<dim3(PB), dim3(PT), 0, stream>>>(in, tsp, abp, out,
                                                 bits2, g_rep, wm, wt, wa);
  snn_finish<<<dim3(1), dim3(256), 0, stream>>>(wm, wt, wa, out);
  snn_expand<<<dim3(2048), dim3(256), 0, stream>>>(bits2, out);
}